// Round 13
// baseline (227.673 us; speedup 1.0000x reference)
//
#include <hip/hip_runtime.h>
#include <stdint.h>

typedef unsigned short u16;
using bf16x8 = __attribute__((ext_vector_type(8))) __bf16;
using s16x8  = __attribute__((ext_vector_type(8))) short;
using f32x4  = __attribute__((ext_vector_type(4))) float;

#define SCALE_Q 0.125f   // 64^-0.5
#define LOG2E 1.44269504088896f

__device__ __forceinline__ u16 f2bf(float f) {
  union { float f; uint32_t u; } v; v.f = f;
  uint32_t u = v.u;
  return (u16)((u + 0x7FFFu + ((u >> 16) & 1)) >> 16);
}

__device__ __forceinline__ bf16x8 ld_frag(const u16* p) {
  return __builtin_bit_cast(bf16x8, *(const s16x8*)p);
}

__device__ __forceinline__ f32x4 MF(bf16x8 a, bf16x8 b, f32x4 c) {
  return __builtin_amdgcn_mfma_f32_16x16x32_bf16(a, b, c, 0, 0, 0);
}

// async global->LDS, 16B per lane. LDS side must be wave-uniform base + lane*16.
__device__ __forceinline__ void gld16(const u16* g, u16* l) {
  __builtin_amdgcn_global_load_lds(
      (const __attribute__((address_space(1))) uint32_t*)g,
      (__attribute__((address_space(3))) uint32_t*)l, 16, 0, 0);
}

// pack two fp32 -> bf16x2 dword (round-half-up)
__device__ __forceinline__ uint32_t pk_bf16(float a, float b) {
  uint32_t u0 = __builtin_bit_cast(uint32_t, a) + 0x8000u;
  uint32_t u1 = __builtin_bit_cast(uint32_t, b) + 0x8000u;
  return __builtin_amdgcn_perm(u1, u0, 0x07060302u);  // [u1.hi16 : u0.hi16]
}

// ---------------- merged prep: cvt x->bf16 (blocks 0..6143), W_qkv^T (next 1728),
// W_proj^T (next 576) ----------------
__global__ void prep_kernel(const float* __restrict__ x, u16* __restrict__ xb,
                            const float* __restrict__ Wq, u16* __restrict__ wqt,
                            const float* __restrict__ Wp, u16* __restrict__ wpt) {
  __shared__ float tile[32][33];
  int bx = blockIdx.x;
  if (bx < 6144) {
    int i = (bx * 256 + threadIdx.x) * 4;
    float4 v = *(const float4*)(x + i);
    uint2 o;
    o.x = (uint32_t)f2bf(v.x) | ((uint32_t)f2bf(v.y) << 16);
    o.y = (uint32_t)f2bf(v.z) | ((uint32_t)f2bf(v.w) << 16);
    *(uint2*)(xb + i) = o;
    return;
  }
  bx -= 6144;
  const float* in;
  u16* out;
  int C, cb, rb;
  const int R = 768;
  if (bx < 1728) { in = Wq; out = wqt; C = 2304; cb = bx % 72; rb = bx / 72; }
  else { bx -= 1728; in = Wp; out = wpt; C = 768; cb = bx % 24; rb = bx / 24; }
  int c0 = cb * 32, r0 = rb * 32;
  int tx = threadIdx.x & 31, ty = threadIdx.x >> 5;
#pragma unroll
  for (int j = 0; j < 32; j += 8)
    tile[ty + j][tx] = in[(size_t)(r0 + ty + j) * C + c0 + tx];
  __syncthreads();
#pragma unroll
  for (int j = 0; j < 32; j += 8)
    out[(size_t)(c0 + ty + j) * R + r0 + tx] = f2bf(tile[tx][ty + j]);
}

// ---------------- QKV GEMM: C[M,N] = A[M,768] * Bt[N,768]^T + bias ----------------
// 128x128 tile, BK=64, 4 waves. Blocks dtype-pure: bn 0..5 Q, 6..11 K, 12..17 V.
// V: LDS transpose -> coalesced 128B stores to V^T (token-PERMUTED within each
// 32-token block: orig token 16g+4k+r at position 8k+4g+r, for attn's register-P).
// Q/K (round 13): LDS-staged epilogue replaces the 64x scalar-2B-store scatter --
// C tile -> smem [m][n] (stride 136 u16, pad kills pow2 conflicts), then each
// thread stores one contiguous 128B half-row (8x uint4). Fewer vmem instrs
// (64 -> 8) and full write coalescing (32B segments -> 128B).
// XCD swizzle: 1152 blocks = 8 XCDs x 144; bijective chunking for A-panel L2 reuse.
__global__ __launch_bounds__(256) void gemm_qkv(
    const u16* __restrict__ A, const u16* __restrict__ Bt, const float* __restrict__ bias,
    u16* __restrict__ q_out, u16* __restrict__ k_out, u16* __restrict__ v_out) {
  constexpr int K = 768;
  __shared__ __align__(16) u16 smem[17408];
  u16* sA = smem;
  u16* sB = smem + 8192;
  const int tid = threadIdx.x;
  const int lane = tid & 63, wave = tid >> 6;
  const int ml = lane & 15, kg = lane >> 4;
  const int wr = wave >> 1, wc = wave & 1;
  const int bid0 = blockIdx.x + blockIdx.y * 18;        // 0..1151
  const int nbid = (bid0 & 7) * 144 + (bid0 >> 3);      // bijective XCD chunking
  const int bn = nbid % 18, bm = nbid / 18;

  f32x4 acc[4][4] = {};
  const u16* Abase = A + (size_t)(bm * 128) * K;
  const u16* Bbase = Bt + (size_t)(bn * 128) * K;

  for (int k0 = 0; k0 < K; k0 += 64) {
#pragma unroll
    for (int p = 0; p < 4; p++) {
      int q = p * 256 + tid;
      int r = q >> 3, s = q & 7, c = s ^ (r & 7);
      gld16(Abase + (size_t)r * K + k0 + c * 8, sA + q * 8);
      gld16(Bbase + (size_t)r * K + k0 + c * 8, sB + q * 8);
    }
    __syncthreads();
#pragma unroll
    for (int kc = 0; kc < 2; kc++) {
      bf16x8 af[4], bfr[4];
      int ac = kc * 4 + kg;
#pragma unroll
      for (int i = 0; i < 4; i++) {
        int arow = wr * 64 + i * 16 + ml;
        af[i] = ld_frag(sA + (arow * 8 + (ac ^ (arow & 7))) * 8);
        int brow = wc * 64 + i * 16 + ml;
        bfr[i] = ld_frag(sB + (brow * 8 + (ac ^ (brow & 7))) * 8);
      }
#pragma unroll
      for (int mi = 0; mi < 4; mi++)
#pragma unroll
        for (int ni = 0; ni < 4; ni++)
          acc[mi][ni] = MF(af[mi], bfr[ni], acc[mi][ni]);
    }
    __syncthreads();
  }

  // C/D layout: col = lane&15, row = (lane>>4)*4 + reg
  if (bn >= 12) {
    // ---- V block: transpose via LDS, store V^T [B,H,D,N] (token-permuted) ----
    uint32_t* t32 = (uint32_t*)smem;  // stride 68 u32 per d row; u32 col mh = tokens 2mh,2mh+1
#pragma unroll
    for (int ni = 0; ni < 4; ni++) {
      int n_local = wc * 64 + ni * 16 + ml;
      float bv = bias[bn * 128 + n_local];
#pragma unroll
      for (int mi = 0; mi < 4; mi++) {
        int mh = wr * 32 + mi * 8 + kg * 2;
        t32[n_local * 68 + mh]     = pk_bf16(acc[mi][ni][0] + bv, acc[mi][ni][1] + bv);
        t32[n_local * 68 + mh + 1] = pk_bf16(acc[mi][ni][2] + bv, acc[mi][ni][3] + bv);
      }
    }
    __syncthreads();
    int row = tid >> 1, seg = tid & 1;
    int dg = (bn - 12) * 128 + row;
    int h = dg >> 6, d = dg & 63;
    int bi = bm >> 4, tok0 = (bm & 15) * 128;
    u16* dst = v_out + ((size_t)(bi * 12 + h) * 64 + d) * 2048 + tok0 + seg * 64;
    const uint32_t* srow = t32 + row * 68;
#pragma unroll
    for (int j = 0; j < 8; j++) {
      int m8 = seg * 8 + j;              // 8-token output chunk in 128-tile
      int c = m8 >> 2, k = m8 & 3;       // 32-block c, permuted sub-chunk k
      // new positions 32c+8k..+7 <- orig tokens {32c+4k..+3, 32c+16+4k..+3}
      const uint32_t* s = srow + 16 * c + 2 * k;
      uint4 u; u.x = s[0]; u.y = s[1]; u.z = s[8]; u.w = s[9];
      *(uint4*)(dst + j * 8) = u;
    }
  } else {
    // ---- Q/K block: LDS-staged epilogue, coalesced 128B stores ----
    u16* dst0 = (bn < 6) ? q_out : k_out;
    float scl = (bn < 6) ? SCALE_Q * LOG2E : 1.0f;  // fold softmax log2e into Q
    u16* e16 = smem;   // [m_local][n_local], stride 136 u16 (128*136 = 17408 exact)
#pragma unroll
    for (int ni = 0; ni < 4; ni++) {
      int n_local = wc * 64 + ni * 16 + ml;
      float bv = bias[bn * 128 + n_local];
#pragma unroll
      for (int mi = 0; mi < 4; mi++)
#pragma unroll
        for (int r = 0; r < 4; r++)
          e16[(wr * 64 + mi * 16 + kg * 4 + r) * 136 + n_local] =
              f2bf((acc[mi][ni][r] + bv) * scl);
    }
    __syncthreads();
    int row = tid >> 1, seg = tid & 1;         // row 0..127, seg = head half
    int n = bn * 128 + seg * 64;
    int rem = (bn < 6) ? n : n - 768;
    int h = rem >> 6;                          // whole 64-d head per seg
    int m = bm * 128 + row;
    int bi = m >> 11, tok = m & 2047;
    const u16* src = e16 + row * 136 + seg * 64;
    u16* dst = dst0 + (size_t)(bi * 12 + h) * 131072 + (size_t)tok * 64;
#pragma unroll
    for (int j = 0; j < 8; j++)
      *(uint4*)(dst + j * 8) = *(const uint4*)(src + j * 8);
  }
}

// ---------------- proj GEMM: 128x64 tile (768 blocks = 3/CU exact) ----------------
// XCD swizzle: 768 = 8 x 96 bijective. Round 13: LDS-staged f32 epilogue --
// C tile -> smem [m][n] f32 (stride 68, 128*68*4 = 34816 B), each thread stores
// one contiguous 128B quarter-row (8x uint4) instead of 32 scalar f32 stores.
__global__ __launch_bounds__(256) void gemm_proj(
    const u16* __restrict__ A, const u16* __restrict__ Bt, const float* __restrict__ bias,
    float* __restrict__ c_out) {
  constexpr int K = 768;
  __shared__ __align__(16) u16 smem[17408];   // 34816 B: sA(16384) + sB(8192) | epilogue f32 tile
  u16* sA = smem;
  u16* sB = smem + 8192;
  const int tid = threadIdx.x;
  const int lane = tid & 63, wave = tid >> 6;
  const int ml = lane & 15, kg = lane >> 4;
  const int bid0 = blockIdx.x + blockIdx.y * 12;        // 0..767
  const int nbid = (bid0 & 7) * 96 + (bid0 >> 3);       // bijective XCD chunking
  const int bn = nbid % 12, bm = nbid / 12;
  f32x4 acc[2][4] = {};
  const u16* Abase = A + (size_t)(bm * 128) * K;
  const u16* Bbase = Bt + (size_t)(bn * 64) * K;

  for (int k0 = 0; k0 < K; k0 += 64) {
#pragma unroll
    for (int p = 0; p < 4; p++) {
      int q = p * 256 + tid;
      int r = q >> 3, s = q & 7, c = s ^ (r & 7);
      gld16(Abase + (size_t)r * K + k0 + c * 8, sA + q * 8);
    }
#pragma unroll
    for (int p = 0; p < 2; p++) {
      int q = p * 256 + tid;
      int r = q >> 3, s = q & 7, c = s ^ (r & 7);
      gld16(Bbase + (size_t)r * K + k0 + c * 8, sB + q * 8);
    }
    __syncthreads();
#pragma unroll
    for (int kc = 0; kc < 2; kc++) {
      int ac = kc * 4 + kg;
      bf16x8 af[2], bfr[4];
#pragma unroll
      for (int i = 0; i < 2; i++) {
        int arow = wave * 32 + i * 16 + ml;
        af[i] = ld_frag(sA + (arow * 8 + (ac ^ (arow & 7))) * 8);
      }
#pragma unroll
      for (int i = 0; i < 4; i++) {
        int brow = i * 16 + ml;
        bfr[i] = ld_frag(sB + (brow * 8 + (ac ^ (brow & 7))) * 8);
      }
#pragma unroll
      for (int mi = 0; mi < 2; mi++)
#pragma unroll
        for (int ni = 0; ni < 4; ni++)
          acc[mi][ni] = MF(af[mi], bfr[ni], acc[mi][ni]);
    }
    __syncthreads();
  }

  // ---- LDS-staged epilogue: [m][n] f32 stride 68, then 128B/thread stores ----
  float* e32 = (float*)smem;
#pragma unroll
  for (int ni = 0; ni < 4; ni++) {
    int n_local = ni * 16 + ml;
    float bv = bias[bn * 64 + n_local];
#pragma unroll
    for (int mi = 0; mi < 2; mi++)
#pragma unroll
      for (int r = 0; r < 4; r++)
        e32[(wave * 32 + mi * 16 + kg * 4 + r) * 68 + n_local] = acc[mi][ni][r] + bv;
  }
  __syncthreads();
  {
    int row = tid >> 1, seg = tid & 1;       // row 0..127, 32-f32 half of the 64-wide tile
    const float* src = e32 + row * 68 + seg * 32;
    float* dst = c_out + (size_t)(bm * 128 + row) * 768 + bn * 64 + seg * 32;
#pragma unroll
    for (int j = 0; j < 8; j++)
      *(uint4*)(dst + j * 4) = *(const uint4*)(src + j * 4);
  }
}

// ---------------- flash attention (register-P, permuted-V, 8 waves) ----------------
// ROUND-9 VERIFIED VERSION (65.0 us best): grid (16, 48) = 768 blocks (3/CU),
// XCD-swizzled, 512 threads / 8 waves, wave owns 16 q. Round-12's 128-key tiles
// (barrier halving) were neutral-negative (66.8) -> reverted. Lagged-PV family
// failed 3x (r1/r2/r11) -> abandoned.
// QK: sc[nt] = mfma(kf, qf): lane (kg,ml) holds S[key=nt*16+kg*4+r][q=q0+ml].
// P in REGISTERS: pf[c] elem j = P[q][key 32c+16(j>>2)+4kg+(j&3)] matches the
// PERMUTED V^T (contiguous conflict-free b128 vf reads; round 6: 0 conflicts).
// l-sum on MFMA pipe (round 8): lacc += MF(pf[c], ones); row layout == O's rows
// -> no epilogue shuffles. Staging: 512 elements <-> 512 threads, 1 gld16 each
// for K and V. exp2 needs no running max: Q carries log2e/8. LDS 32KB.
__global__ __launch_bounds__(512, 6) void attn_kernel(
    const u16* __restrict__ qs, const u16* __restrict__ ks, const u16* __restrict__ vt,
    float* __restrict__ attn_f32, u16* __restrict__ attn_bf) {
  __shared__ __align__(16) u16 sK[2][4096];   // swizzled [key][dim]
  __shared__ __align__(16) u16 sV[2][4096];   // swizzled [dim][key-permuted]
  const int tid = threadIdx.x, lane = tid & 63, wave = tid >> 6;
  const int ml = lane & 15, kg = lane >> 4;
  const int m7 = ml & 7;
  // XCD swizzle (round 3: FETCH 104 -> 18.5MB)
  const int bid  = blockIdx.x + (blockIdx.y << 4);   // 0..767
  const int slot = bid >> 3;                          // 0..95
  const int bh   = (bid & 7) * 6 + (slot >> 4);
  const int q0   = (slot & 15) * 128 + wave * 16;     // wave owns 16 q
  const size_t base = (size_t)bh * 131072;

  bf16x8 qf[2];
  {
    const u16* qp = qs + base + (size_t)(q0 + ml) * 64 + kg * 8;
    qf[0] = ld_frag(qp);
    qf[1] = ld_frag(qp + 32);
  }
  // ones B-fragment for the l-sum MFMA (bf16 1.0 = 0x3F80)
  uint4 uo; uo.x = uo.y = uo.z = uo.w = 0x3F803F80u;
  const bf16x8 onesf = __builtin_bit_cast(bf16x8, uo);
  f32x4 lacc = {};   // lane reg r: l[q = q0 + kg*4 + r]
  f32x4 O[4] = {};

  // hoisted per-lane LDS pointers (u16 units); use: base + compile-time offset
  const u16* kbase[2] = { &sK[0][ml * 64 + ((0 + kg) ^ m7) * 8],
                          &sK[0][ml * 64 + ((4 + kg) ^ m7) * 8] };
  const u16* vbase[2] = { &sV[0][ml * 64 + ((0 + kg) ^ m7) * 8],
                          &sV[0][ml * 64 + ((4 + kg) ^ m7) * 8] };

  // hoisted staging pointers: thread t handles element t (512 of 512)
  const int r0 = tid >> 3, c0 = (tid & 7) ^ (r0 & 7);
  const u16* kgp = ks + base + r0 * 64 + c0 * 8;     // + kt*64
  const u16* vgp = vt + base + r0 * 2048 + c0 * 8;   // + kt

  auto stage = [&](int b, int kt) {
    gld16(kgp + kt * 64, &sK[b][tid * 8]);
    gld16(vgp + kt,      &sV[b][tid * 8]);
  };

  stage(0, 0);
  for (int kt = 0; kt < 2048; kt += 128) {
#pragma unroll
    for (int half = 0; half < 2; half++) {   // buf = half (compile-time after unroll)
      const int cur = kt + half * 64;
      __syncthreads();  // current buf's DMA complete; prev reads done
      if (cur + 64 < 2048) stage(half ^ 1, cur + 64);

      // ---- S^T = K Q^T for 64 keys ----
      f32x4 sc[4] = {};
#pragma unroll
      for (int nt = 0; nt < 4; nt++)
#pragma unroll
        for (int kc = 0; kc < 2; kc++) {
          bf16x8 kf = ld_frag(kbase[kc] + nt * 1024 + half * 4096);
          sc[nt] = MF(kf, qf[kc], sc[nt]);
        }

      // ---- p = exp2(s); pack into register A-fragments (pk_bf16, no LDS) ----
      bf16x8 pf[2];
#pragma unroll
      for (int c = 0; c < 2; c++) {
        f32x4 pa, pb;
#pragma unroll
        for (int r = 0; r < 4; r++) {
          pa[r] = __builtin_amdgcn_exp2f(sc[2 * c][r]);
          pb[r] = __builtin_amdgcn_exp2f(sc[2 * c + 1][r]);
        }
        uint4 u;
        u.x = pk_bf16(pa[0], pa[1]);
        u.y = pk_bf16(pa[2], pa[3]);
        u.z = pk_bf16(pb[0], pb[1]);
        u.w = pk_bf16(pb[2], pb[3]);
        pf[c] = __builtin_bit_cast(bf16x8, u);
      }

      // ---- l-sum on MFMA pipe ----
      lacc = MF(pf[0], onesf, lacc);
      lacc = MF(pf[1], onesf, lacc);

      // ---- O += P V (vf: contiguous conflict-free b128) ----
#pragma unroll
      for (int c = 0; c < 2; c++)
#pragma unroll
        for (int nt2 = 0; nt2 < 4; nt2++) {
          bf16x8 vf = ld_frag(vbase[c] + nt2 * 1024 + half * 4096);
          O[nt2] = MF(pf[c], vf, O[nt2]);
        }
    }
  }

  // epilogue: O rows q=kg*4+r, cols d=nt2*16+ml; l already in row layout
  int b = bh / 12, h = bh - b * 12;
#pragma unroll
  for (int r = 0; r < 4; r++) {
    float inv = __builtin_amdgcn_rcpf(lacc[r]);
    int qrow = q0 + kg * 4 + r;
    size_t rowoff = ((size_t)(b * 2048 + qrow)) * 768 + h * 64;
#pragma unroll
    for (int nt2 = 0; nt2 < 4; nt2++) {
      float v = O[nt2][r] * inv;
      int d = nt2 * 16 + ml;
      attn_f32[rowoff + d] = v;
      attn_bf[rowoff + d] = f2bf(v);
    }
  }
}

extern "C" void kernel_launch(void* const* d_in, const int* in_sizes, int n_in,
                              void* d_out, int out_size, void* d_ws, size_t ws_size,
                              hipStream_t stream) {
  const float* x      = (const float*)d_in[0];
  const float* W_qkv  = (const float*)d_in[1];
  const float* b_qkv  = (const float*)d_in[2];
  const float* W_proj = (const float*)d_in[3];
  const float* b_proj = (const float*)d_in[4];
  float* out      = (float*)d_out;                  // [8192,768]
  float* attn_out = out + (size_t)8192 * 768;       // [8192,768]

  char* ws = (char*)d_ws;
  const size_t SZ_XB = (size_t)8192 * 768 * 2;      // 12.58 MB
  u16* xb      = (u16*)(ws);                         // reused as bf16 attn_out for proj
  u16* wqkv_t  = (u16*)(ws + SZ_XB);
  u16* wproj_t = (u16*)(ws + SZ_XB + 3538944);
  u16* qs      = (u16*)(ws + SZ_XB + 3538944 + 1179648);
  u16* ks      = (u16*)((char*)qs + SZ_XB);
  u16* vt      = (u16*)((char*)ks + SZ_XB);          // V^T [B,H,D,N] (token-permuted)
  u16* ab      = xb;

  prep_kernel<<<6144 + 1728 + 576, 256, 0, stream>>>(x, xb, W_qkv, wqkv_t, W_proj, wproj_t);
  gemm_qkv<<<dim3(18, 64), 256, 0, stream>>>(xb, wqkv_t, b_qkv, qs, ks, vt);
  attn_kernel<<<dim3(16, 48), 512, 0, stream>>>(qs, ks, vt, attn_out, ab);
  gemm_proj<<<dim3(12, 64), 256, 0, stream>>>(ab, wproj_t, b_proj, out);
}

// Round 14
// 212.028 us; speedup vs baseline: 1.0738x; 1.0738x over previous
//
#include <hip/hip_runtime.h>
#include <stdint.h>

typedef unsigned short u16;
using bf16x8 = __attribute__((ext_vector_type(8))) __bf16;
using s16x8  = __attribute__((ext_vector_type(8))) short;
using f32x4  = __attribute__((ext_vector_type(4))) float;

#define SCALE_Q 0.125f   // 64^-0.5
#define LOG2E 1.44269504088896f

__device__ __forceinline__ u16 f2bf(float f) {
  union { float f; uint32_t u; } v; v.f = f;
  uint32_t u = v.u;
  return (u16)((u + 0x7FFFu + ((u >> 16) & 1)) >> 16);
}

__device__ __forceinline__ bf16x8 ld_frag(const u16* p) {
  return __builtin_bit_cast(bf16x8, *(const s16x8*)p);
}

__device__ __forceinline__ f32x4 MF(bf16x8 a, bf16x8 b, f32x4 c) {
  return __builtin_amdgcn_mfma_f32_16x16x32_bf16(a, b, c, 0, 0, 0);
}

// async global->LDS, 16B per lane. LDS side must be wave-uniform base + lane*16.
__device__ __forceinline__ void gld16(const u16* g, u16* l) {
  __builtin_amdgcn_global_load_lds(
      (const __attribute__((address_space(1))) uint32_t*)g,
      (__attribute__((address_space(3))) uint32_t*)l, 16, 0, 0);
}

// pack two fp32 -> bf16x2 dword (round-half-up)
__device__ __forceinline__ uint32_t pk_bf16(float a, float b) {
  uint32_t u0 = __builtin_bit_cast(uint32_t, a) + 0x8000u;
  uint32_t u1 = __builtin_bit_cast(uint32_t, b) + 0x8000u;
  return __builtin_amdgcn_perm(u1, u0, 0x07060302u);  // [u1.hi16 : u0.hi16]
}

// ---------------- merged prep: cvt x->bf16 (blocks 0..6143), W_qkv^T (next 1728),
// W_proj^T (next 576) ----------------
__global__ void prep_kernel(const float* __restrict__ x, u16* __restrict__ xb,
                            const float* __restrict__ Wq, u16* __restrict__ wqt,
                            const float* __restrict__ Wp, u16* __restrict__ wpt) {
  __shared__ float tile[32][33];
  int bx = blockIdx.x;
  if (bx < 6144) {
    int i = (bx * 256 + threadIdx.x) * 4;
    float4 v = *(const float4*)(x + i);
    uint2 o;
    o.x = (uint32_t)f2bf(v.x) | ((uint32_t)f2bf(v.y) << 16);
    o.y = (uint32_t)f2bf(v.z) | ((uint32_t)f2bf(v.w) << 16);
    *(uint2*)(xb + i) = o;
    return;
  }
  bx -= 6144;
  const float* in;
  u16* out;
  int C, cb, rb;
  const int R = 768;
  if (bx < 1728) { in = Wq; out = wqt; C = 2304; cb = bx % 72; rb = bx / 72; }
  else { bx -= 1728; in = Wp; out = wpt; C = 768; cb = bx % 24; rb = bx / 24; }
  int c0 = cb * 32, r0 = rb * 32;
  int tx = threadIdx.x & 31, ty = threadIdx.x >> 5;
#pragma unroll
  for (int j = 0; j < 32; j += 8)
    tile[ty + j][tx] = in[(size_t)(r0 + ty + j) * C + c0 + tx];
  __syncthreads();
#pragma unroll
  for (int j = 0; j < 32; j += 8)
    out[(size_t)(c0 + ty + j) * R + r0 + tx] = f2bf(tile[tx][ty + j]);
}

// ---------------- QKV GEMM: C[M,N] = A[M,768] * Bt[N,768]^T + bias ----------------
// Round 14: 128x96 tile -> grid 24x64 = 1536 blocks = 6.0/CU EXACT (was 1152 =
// 4.5/CU: half the CUs ran 5 blocks, half 4 -> ~11% tail idle). 768/96 = 8, so
// blocks stay dtype-pure: bn 0..7 Q, 8..15 K, 16..23 V. BK=64, 4 waves (wr,wc),
// wc spans 48 cols (3 fragments). Epilogues are the VERIFIED scatter forms
// (round-13's LDS-staged epilogue cost +10us: scatter stores are fire-and-forget;
// reverted). V: LDS transpose -> coalesced 128B stores to V^T, token-PERMUTED
// within each 32-token block (orig token 16g+4k+r at position 8k+4g+r) for
// attn's register-P. XCD swizzle: 1536 = 8 x 192 bijective.
__global__ __launch_bounds__(256) void gemm_qkv(
    const u16* __restrict__ A, const u16* __restrict__ Bt, const float* __restrict__ bias,
    u16* __restrict__ q_out, u16* __restrict__ k_out, u16* __restrict__ v_out) {
  constexpr int K = 768;
  __shared__ __align__(16) u16 smem[14336];   // sA 128x64 (16384B) + sB 96x64 (12288B)
  u16* sA = smem;
  u16* sB = smem + 8192;
  const int tid = threadIdx.x;
  const int lane = tid & 63, wave = tid >> 6;
  const int ml = lane & 15, kg = lane >> 4;
  const int wr = wave >> 1, wc = wave & 1;
  const int bid0 = blockIdx.x + blockIdx.y * 24;        // 0..1535
  const int nbid = (bid0 & 7) * 192 + (bid0 >> 3);      // bijective XCD chunking
  const int bn = nbid % 24, bm = nbid / 24;

  f32x4 acc[4][3] = {};
  const u16* Abase = A + (size_t)(bm * 128) * K;
  const u16* Bbase = Bt + (size_t)(bn * 96) * K;

  for (int k0 = 0; k0 < K; k0 += 64) {
#pragma unroll
    for (int p = 0; p < 4; p++) {
      int q = p * 256 + tid;
      int r = q >> 3, s = q & 7, c = s ^ (r & 7);
      gld16(Abase + (size_t)r * K + k0 + c * 8, sA + q * 8);
    }
#pragma unroll
    for (int p = 0; p < 3; p++) {
      int q = p * 256 + tid;
      int r = q >> 3, s = q & 7, c = s ^ (r & 7);
      gld16(Bbase + (size_t)r * K + k0 + c * 8, sB + q * 8);
    }
    __syncthreads();
#pragma unroll
    for (int kc = 0; kc < 2; kc++) {
      bf16x8 af[4], bfr[3];
      int ac = kc * 4 + kg;
#pragma unroll
      for (int i = 0; i < 4; i++) {
        int arow = wr * 64 + i * 16 + ml;
        af[i] = ld_frag(sA + (arow * 8 + (ac ^ (arow & 7))) * 8);
      }
#pragma unroll
      for (int i = 0; i < 3; i++) {
        int brow = wc * 48 + i * 16 + ml;
        bfr[i] = ld_frag(sB + (brow * 8 + (ac ^ (brow & 7))) * 8);
      }
#pragma unroll
      for (int mi = 0; mi < 4; mi++)
#pragma unroll
        for (int ni = 0; ni < 3; ni++)
          acc[mi][ni] = MF(af[mi], bfr[ni], acc[mi][ni]);
    }
    __syncthreads();
  }

  // C/D layout: col = lane&15, row = (lane>>4)*4 + reg
  if (bn >= 16) {
    // ---- V block: transpose via LDS, store V^T [B,H,D,N] (token-permuted) ----
    uint32_t* t32 = (uint32_t*)smem;  // [n_local 0..95][token-pair mh 0..63], stride 68
#pragma unroll
    for (int ni = 0; ni < 3; ni++) {
      int n_local = wc * 48 + ni * 16 + ml;
      float bv = bias[bn * 96 + n_local];
#pragma unroll
      for (int mi = 0; mi < 4; mi++) {
        int mh = wr * 32 + mi * 8 + kg * 2;
        t32[n_local * 68 + mh]     = pk_bf16(acc[mi][ni][0] + bv, acc[mi][ni][1] + bv);
        t32[n_local * 68 + mh + 1] = pk_bf16(acc[mi][ni][2] + bv, acc[mi][ni][3] + bv);
      }
    }
    __syncthreads();
    if (tid < 192) {
      int row = tid >> 1, seg = tid & 1;       // row = d-dim 0..95
      int dg = (bn - 16) * 96 + row;           // 0..767
      int h = dg >> 6, d = dg & 63;
      int bi = bm >> 4, tok0 = (bm & 15) * 128;
      u16* dst = v_out + ((size_t)(bi * 12 + h) * 64 + d) * 2048 + tok0 + seg * 64;
      const uint32_t* srow = t32 + row * 68;
#pragma unroll
      for (int j = 0; j < 8; j++) {
        int m8 = seg * 8 + j;              // 8-token output chunk in 128-tile
        int c = m8 >> 2, k = m8 & 3;       // 32-block c, permuted sub-chunk k
        // new positions 32c+8k..+7 <- orig tokens {32c+4k..+3, 32c+16+4k..+3}
        const uint32_t* s = srow + 16 * c + 2 * k;
        uint4 u; u.x = s[0]; u.y = s[1]; u.z = s[8]; u.w = s[9];
        *(uint4*)(dst + j * 8) = u;
      }
    }
  } else {
    u16* dst = (bn < 8) ? q_out : k_out;
    float scl = (bn < 8) ? SCALE_Q * LOG2E : 1.0f;  // fold softmax log2e into Q
#pragma unroll
    for (int ni = 0; ni < 3; ni++) {
      int n = bn * 96 + wc * 48 + ni * 16 + ml;
      int rem = (bn < 8) ? n : n - 768;
      int h = rem >> 6, d = rem & 63;
      float bv = bias[n];
#pragma unroll
      for (int mi = 0; mi < 4; mi++) {
        int m0 = bm * 128 + wr * 64 + mi * 16 + kg * 4;
#pragma unroll
        for (int r = 0; r < 4; r++) {
          int m = m0 + r;
          int bi = m >> 11, tok = m & 2047;
          dst[(size_t)(bi * 12 + h) * 131072 + (size_t)tok * 64 + d] = f2bf((acc[mi][ni][r] + bv) * scl);
        }
      }
    }
  }
}

// ---------------- proj GEMM: 128x64 tile (768 blocks = 3/CU exact) ----------------
// XCD swizzle: 768 = 8 x 96 bijective. Verified scatter epilogue (r3-r12).
__global__ __launch_bounds__(256) void gemm_proj(
    const u16* __restrict__ A, const u16* __restrict__ Bt, const float* __restrict__ bias,
    float* __restrict__ c_out) {
  constexpr int K = 768;
  __shared__ __align__(16) u16 sA[128 * 64];
  __shared__ __align__(16) u16 sB[64 * 64];
  const int tid = threadIdx.x;
  const int lane = tid & 63, wave = tid >> 6;
  const int ml = lane & 15, kg = lane >> 4;
  const int bid0 = blockIdx.x + blockIdx.y * 12;        // 0..767
  const int nbid = (bid0 & 7) * 96 + (bid0 >> 3);       // bijective XCD chunking
  const int bn = nbid % 12, bm = nbid / 12;
  f32x4 acc[2][4] = {};
  const u16* Abase = A + (size_t)(bm * 128) * K;
  const u16* Bbase = Bt + (size_t)(bn * 64) * K;

  for (int k0 = 0; k0 < K; k0 += 64) {
#pragma unroll
    for (int p = 0; p < 4; p++) {
      int q = p * 256 + tid;
      int r = q >> 3, s = q & 7, c = s ^ (r & 7);
      gld16(Abase + (size_t)r * K + k0 + c * 8, sA + q * 8);
    }
#pragma unroll
    for (int p = 0; p < 2; p++) {
      int q = p * 256 + tid;
      int r = q >> 3, s = q & 7, c = s ^ (r & 7);
      gld16(Bbase + (size_t)r * K + k0 + c * 8, sB + q * 8);
    }
    __syncthreads();
#pragma unroll
    for (int kc = 0; kc < 2; kc++) {
      int ac = kc * 4 + kg;
      bf16x8 af[2], bfr[4];
#pragma unroll
      for (int i = 0; i < 2; i++) {
        int arow = wave * 32 + i * 16 + ml;
        af[i] = ld_frag(sA + (arow * 8 + (ac ^ (arow & 7))) * 8);
      }
#pragma unroll
      for (int i = 0; i < 4; i++) {
        int brow = i * 16 + ml;
        bfr[i] = ld_frag(sB + (brow * 8 + (ac ^ (brow & 7))) * 8);
      }
#pragma unroll
      for (int mi = 0; mi < 2; mi++)
#pragma unroll
        for (int ni = 0; ni < 4; ni++)
          acc[mi][ni] = MF(af[mi], bfr[ni], acc[mi][ni]);
    }
    __syncthreads();
  }
#pragma unroll
  for (int ni = 0; ni < 4; ni++) {
    int n = bn * 64 + ni * 16 + ml;
    float bv = bias[n];
#pragma unroll
    for (int mi = 0; mi < 2; mi++) {
      int m0 = bm * 128 + wave * 32 + mi * 16 + kg * 4;
#pragma unroll
      for (int r = 0; r < 4; r++)
        c_out[(size_t)(m0 + r) * 768 + n] = acc[mi][ni][r] + bv;
    }
  }
}

// ---------------- flash attention (register-P, permuted-V, 8 waves) ----------------
// ROUND-9 VERIFIED VERSION (65.0 us best): grid (16, 48) = 768 blocks (3/CU),
// XCD-swizzled, 512 threads / 8 waves, wave owns 16 q. Round-12's 128-key tiles
// (barrier halving) were neutral-negative -> reverted. Lagged-PV family failed
// 3x (r1/r2/r11) -> abandoned.
// QK: sc[nt] = mfma(kf, qf): lane (kg,ml) holds S[key=nt*16+kg*4+r][q=q0+ml].
// P in REGISTERS: pf[c] elem j = P[q][key 32c+16(j>>2)+4kg+(j&3)] matches the
// PERMUTED V^T (contiguous conflict-free b128 vf reads; round 6: 0 conflicts).
// l-sum on MFMA pipe (round 8): lacc += MF(pf[c], ones); row layout == O's rows
// -> no epilogue shuffles. Staging: 512 elements <-> 512 threads, 1 gld16 each
// for K and V. exp2 needs no running max: Q carries log2e/8. LDS 32KB.
__global__ __launch_bounds__(512, 6) void attn_kernel(
    const u16* __restrict__ qs, const u16* __restrict__ ks, const u16* __restrict__ vt,
    float* __restrict__ attn_f32, u16* __restrict__ attn_bf) {
  __shared__ __align__(16) u16 sK[2][4096];   // swizzled [key][dim]
  __shared__ __align__(16) u16 sV[2][4096];   // swizzled [dim][key-permuted]
  const int tid = threadIdx.x, lane = tid & 63, wave = tid >> 6;
  const int ml = lane & 15, kg = lane >> 4;
  const int m7 = ml & 7;
  // XCD swizzle (round 3: FETCH 104 -> 18.5MB)
  const int bid  = blockIdx.x + (blockIdx.y << 4);   // 0..767
  const int slot = bid >> 3;                          // 0..95
  const int bh   = (bid & 7) * 6 + (slot >> 4);
  const int q0   = (slot & 15) * 128 + wave * 16;     // wave owns 16 q
  const size_t base = (size_t)bh * 131072;

  bf16x8 qf[2];
  {
    const u16* qp = qs + base + (size_t)(q0 + ml) * 64 + kg * 8;
    qf[0] = ld_frag(qp);
    qf[1] = ld_frag(qp + 32);
  }
  // ones B-fragment for the l-sum MFMA (bf16 1.0 = 0x3F80)
  uint4 uo; uo.x = uo.y = uo.z = uo.w = 0x3F803F80u;
  const bf16x8 onesf = __builtin_bit_cast(bf16x8, uo);
  f32x4 lacc = {};   // lane reg r: l[q = q0 + kg*4 + r]
  f32x4 O[4] = {};

  // hoisted per-lane LDS pointers (u16 units); use: base + compile-time offset
  const u16* kbase[2] = { &sK[0][ml * 64 + ((0 + kg) ^ m7) * 8],
                          &sK[0][ml * 64 + ((4 + kg) ^ m7) * 8] };
  const u16* vbase[2] = { &sV[0][ml * 64 + ((0 + kg) ^ m7) * 8],
                          &sV[0][ml * 64 + ((4 + kg) ^ m7) * 8] };

  // hoisted staging pointers: thread t handles element t (512 of 512)
  const int r0 = tid >> 3, c0 = (tid & 7) ^ (r0 & 7);
  const u16* kgp = ks + base + r0 * 64 + c0 * 8;     // + kt*64
  const u16* vgp = vt + base + r0 * 2048 + c0 * 8;   // + kt

  auto stage = [&](int b, int kt) {
    gld16(kgp + kt * 64, &sK[b][tid * 8]);
    gld16(vgp + kt,      &sV[b][tid * 8]);
  };

  stage(0, 0);
  for (int kt = 0; kt < 2048; kt += 128) {
#pragma unroll
    for (int half = 0; half < 2; half++) {   // buf = half (compile-time after unroll)
      const int cur = kt + half * 64;
      __syncthreads();  // current buf's DMA complete; prev reads done
      if (cur + 64 < 2048) stage(half ^ 1, cur + 64);

      // ---- S^T = K Q^T for 64 keys ----
      f32x4 sc[4] = {};
#pragma unroll
      for (int nt = 0; nt < 4; nt++)
#pragma unroll
        for (int kc = 0; kc < 2; kc++) {
          bf16x8 kf = ld_frag(kbase[kc] + nt * 1024 + half * 4096);
          sc[nt] = MF(kf, qf[kc], sc[nt]);
        }

      // ---- p = exp2(s); pack into register A-fragments (pk_bf16, no LDS) ----
      bf16x8 pf[2];
#pragma unroll
      for (int c = 0; c < 2; c++) {
        f32x4 pa, pb;
#pragma unroll
        for (int r = 0; r < 4; r++) {
          pa[r] = __builtin_amdgcn_exp2f(sc[2 * c][r]);
          pb[r] = __builtin_amdgcn_exp2f(sc[2 * c + 1][r]);
        }
        uint4 u;
        u.x = pk_bf16(pa[0], pa[1]);
        u.y = pk_bf16(pa[2], pa[3]);
        u.z = pk_bf16(pb[0], pb[1]);
        u.w = pk_bf16(pb[2], pb[3]);
        pf[c] = __builtin_bit_cast(bf16x8, u);
      }

      // ---- l-sum on MFMA pipe ----
      lacc = MF(pf[0], onesf, lacc);
      lacc = MF(pf[1], onesf, lacc);

      // ---- O += P V (vf: contiguous conflict-free b128) ----
#pragma unroll
      for (int c = 0; c < 2; c++)
#pragma unroll
        for (int nt2 = 0; nt2 < 4; nt2++) {
          bf16x8 vf = ld_frag(vbase[c] + nt2 * 1024 + half * 4096);
          O[nt2] = MF(pf[c], vf, O[nt2]);
        }
    }
  }

  // epilogue: O rows q=kg*4+r, cols d=nt2*16+ml; l already in row layout
  int b = bh / 12, h = bh - b * 12;
#pragma unroll
  for (int r = 0; r < 4; r++) {
    float inv = __builtin_amdgcn_rcpf(lacc[r]);
    int qrow = q0 + kg * 4 + r;
    size_t rowoff = ((size_t)(b * 2048 + qrow)) * 768 + h * 64;
#pragma unroll
    for (int nt2 = 0; nt2 < 4; nt2++) {
      float v = O[nt2][r] * inv;
      int d = nt2 * 16 + ml;
      attn_f32[rowoff + d] = v;
      attn_bf[rowoff + d] = f2bf(v);
    }
  }
}

extern "C" void kernel_launch(void* const* d_in, const int* in_sizes, int n_in,
                              void* d_out, int out_size, void* d_ws, size_t ws_size,
                              hipStream_t stream) {
  const float* x      = (const float*)d_in[0];
  const float* W_qkv  = (const float*)d_in[1];
  const float* b_qkv  = (const float*)d_in[2];
  const float* W_proj = (const float*)d_in[3];
  const float* b_proj = (const float*)d_in[4];
  float* out      = (float*)d_out;                  // [8192,768]
  float* attn_out = out + (size_t)8192 * 768;       // [8192,768]

  char* ws = (char*)d_ws;
  const size_t SZ_XB = (size_t)8192 * 768 * 2;      // 12.58 MB
  u16* xb      = (u16*)(ws);                         // reused as bf16 attn_out for proj
  u16* wqkv_t  = (u16*)(ws + SZ_XB);
  u16* wproj_t = (u16*)(ws + SZ_XB + 3538944);
  u16* qs      = (u16*)(ws + SZ_XB + 3538944 + 1179648);
  u16* ks      = (u16*)((char*)qs + SZ_XB);
  u16* vt      = (u16*)((char*)ks + SZ_XB);          // V^T [B,H,D,N] (token-permuted)
  u16* ab      = xb;

  prep_kernel<<<6144 + 1728 + 576, 256, 0, stream>>>(x, xb, W_qkv, wqkv_t, W_proj, wproj_t);
  gemm_qkv<<<dim3(24, 64), 256, 0, stream>>>(xb, wqkv_t, b_qkv, qs, ks, vt);
  attn_kernel<<<dim3(16, 48), 512, 0, stream>>>(qs, ks, vt, attn_out, ab);
  gemm_proj<<<dim3(12, 64), 256, 0, stream>>>(ab, wproj_t, b_proj, out);
}